// Round 5
// baseline (3001.412 us; speedup 1.0000x reference)
//
#include <hip/hip_runtime.h>

// LIF neuron scan, speculative time-chunked (two-pass), bit-exact.
//
// Round-4 measurement: 1 wave/SIMD is latency/issue-bound at ~139 cy/step
// (VALUBusy 3.08% GPU-wide = ~49% on the 64 active SIMDs). More waves is the
// only lever below the ~109 us single-wave issue floor -> parallelize TIME.
//
// Scheme: T=8192 split into C=32 chunks of L=256 steps. Pass 1 simulates every
// chunk in parallel, each preceded by a W=256-step warmup from a canonical
// state (v_reset, non-refractory). LIF contracts (dv/dv_prev = 1-1/tau = 0.9,
// and v_rest - v is EXACT by Sterbenz), so warmup bit-merges with the true
// trajectory w.h.p. (~175 steps typical); coincident spikes merge exactly.
// Pass 1 records entry state S[c] (post-warmup) and exit state E[c] per
// (chunk, neuron) in d_ws. Pass 2 walks chunks per neuron: if the true state
// bit-matches S[c], the chunk's speculative outputs are PROVABLY exact ->
// adopt E[c]. Else re-simulate the chunk (identical rounded ops), early-
// exiting when a true spike coincides with a speculative spike (state then
// provably identical). Correctness never depends on merging -- only speed.
//
// Numerics identical to the validated Round-3 kernel (absmax 0.0): _rn
// intrinsics in reference op order; Markstein 2-FMA correctly-rounded
// divisions; integer refractory end-time (exactly ceil(refr/DT) steps).

#define N_NEURONS 4096
#define T_STEPS   8192
#define BN        64                       // threads per block = 1 wave
#define L_CHUNK   256                      // steps per chunk
#define W_WARM    256                      // warmup steps (c >= 1)
#define C_CHUNKS  (T_STEPS / L_CHUNK)      // 32

__device__ __forceinline__ float div_rn_fast(float a, float b, float rb) {
    // rb = RN(1/b), b normal; returns RN(a/b) for normal a,b,quotient (Markstein).
    const float q = __fmul_rn(a, rb);
    const float e = __fmaf_rn(-b, q, a);
    return __fmaf_rn(e, rb, q);
}

// one exact LIF step; updates v, a, refr_end; returns spike bool
#define LIF_STEP(w, t, v, a, refr_end, sp_out)                                \
    {                                                                         \
        const bool  inr   = (t) < (refr_end);                                 \
        const float u     = __fadd_rn((a), (w));                              \
        const float dv    = div_rn_fast(u, tau_m, rcp_tau);                   \
        const float vi    = __fadd_rn((v), dv);                               \
        const bool  cross = vi >= v_th;                                       \
        const bool  rst   = inr || cross;                                     \
        const float a_ch  = __fsub_rn(v_rest, vi);                            \
        (v) = rst ? v_rst : vi;                                               \
        (a) = rst ? a_rst : a_ch;                                             \
        (sp_out) = (!inr) && cross;                                           \
        (refr_end) = (sp_out) ? ((t) + 1 + n_refr) : (refr_end);              \
    }

__global__ __launch_bounds__(BN)
void lif_pass1(const float* __restrict__ I,
               const float* __restrict__ p_tau,
               const float* __restrict__ p_vth,
               const float* __restrict__ p_vreset,
               const float* __restrict__ p_rm,
               const float* __restrict__ p_vrest,
               const float* __restrict__ p_refr,
               float* __restrict__ out,
               float* __restrict__ ws)
{
    const int lane = threadIdx.x;
    const int c    = blockIdx.x & (C_CHUNKS - 1);     // chunk id
    const int nb   = blockIdx.x / C_CHUNKS;           // neuron block
    const int n    = nb * BN + lane;

    const float tau_m    = p_tau[0];
    const float v_th     = p_vth[0];
    const float v_rst    = p_vreset[0];
    const float r_m      = p_rm[0];
    const float v_rest   = p_vrest[0];
    const float refr_set = __fdiv_rn(p_refr[0], 1.0f);
    const int   n_refr   = (int)ceilf(refr_set);
    const float rcp_tau  = __fdiv_rn(1.0f, tau_m);
    const float rcp_1k   = __fdiv_rn(1.0f, 1000.0f);
    const float a_rst    = __fsub_rn(v_rest, v_rst);

    const float4* rowI4 = reinterpret_cast<const float4*>(I   + (size_t)n * T_STEPS);
    float4*       rowO4 = reinterpret_cast<float4*>      (out + (size_t)n * T_STEPS);

    const int tmain = c * L_CHUNK;        // first main step of this chunk
    float v, a, prev;
    int   refr_end;

    if (c == 0) {                         // exact start: v[0] = v_rest
        v = v_rest; a = __fsub_rn(v_rest, v_rest); refr_end = 0; prev = 0.0f;
    } else {                              // canonical guess + warmup
        v = v_rst; a = a_rst; refr_end = tmain - W_WARM; prev = 0.0f;
        for (int wt = 0; wt < W_WARM / 32; ++wt) {
            const int tb = tmain - W_WARM + wt * 32;
            float4 xb[8];
            #pragma unroll
            for (int j = 0; j < 8; ++j) xb[j] = rowI4[tb / 4 + j];
            #pragma unroll
            for (int j = 0; j < 8; ++j) {
                const float4 x = xb[j];
                #pragma unroll
                for (int k = 0; k < 4; ++k) {
                    const int   t  = tb + 4 * j + k;   // all < tmain <= T-L < T-1
                    const float xi = (k == 0) ? x.x : (k == 1) ? x.y : (k == 2) ? x.z : x.w;
                    const float w  = __fmul_rn(r_m, div_rn_fast(xi, 1000.0f, rcp_1k));
                    bool sp;
                    LIF_STEP(w, t, v, a, refr_end, sp);
                    prev = sp ? 1.0f : 0.0f;
                }
            }
        }
    }

    // ws planes, each C*N floats: vS pS rS(int) vE pE rE(int)
    float* vS = ws + 0 * C_CHUNKS * N_NEURONS;
    float* pS = ws + 1 * C_CHUNKS * N_NEURONS;
    int*   rS = (int*)(ws + 2 * C_CHUNKS * N_NEURONS);
    float* vE = ws + 3 * C_CHUNKS * N_NEURONS;
    float* pE = ws + 4 * C_CHUNKS * N_NEURONS;
    int*   rE = (int*)(ws + 5 * C_CHUNKS * N_NEURONS);
    const int sidx = c * N_NEURONS + n;

    vS[sidx] = v; pS[sidx] = prev; rS[sidx] = refr_end;   // entry state S[c]

    // main: steps tmain .. tmain+L-1; chunk owns output columns [tmain, tmain+L)
    for (int mt = 0; mt < L_CHUNK / 32; ++mt) {
        const int tb = tmain + mt * 32;
        float4 xb[8];
        #pragma unroll
        for (int j = 0; j < 8; ++j) xb[j] = rowI4[tb / 4 + j];
        #pragma unroll
        for (int j = 0; j < 8; ++j) {
            const float4 x  = xb[j];
            const int    c0 = tb + 4 * j;
            float4 s;
            s.x = prev;                    // column c0 = spike of step c0-1
            #pragma unroll
            for (int k = 0; k < 4; ++k) {
                const int t = c0 + k;
                float spf = 0.0f;
                if (t < T_STEPS - 1) {     // uniform guard (last chunk only)
                    const float xi = (k == 0) ? x.x : (k == 1) ? x.y : (k == 2) ? x.z : x.w;
                    const float w  = __fmul_rn(r_m, div_rn_fast(xi, 1000.0f, rcp_1k));
                    bool sp;
                    LIF_STEP(w, t, v, a, refr_end, sp);
                    spf = sp ? 1.0f : 0.0f;
                }
                if      (k == 0) s.y = spf;
                else if (k == 1) s.z = spf;
                else if (k == 2) s.w = spf;
                else             prev = spf;
            }
            rowO4[c0 / 4] = s;
        }
    }

    vE[sidx] = v; pE[sidx] = prev; rE[sidx] = refr_end;   // exit state E[c]
}

__global__ __launch_bounds__(BN)
void lif_pass2(const float* __restrict__ I,
               const float* __restrict__ p_tau,
               const float* __restrict__ p_vth,
               const float* __restrict__ p_vreset,
               const float* __restrict__ p_rm,
               const float* __restrict__ p_vrest,
               const float* __restrict__ p_refr,
               float* __restrict__ out,
               const float* __restrict__ ws)
{
    const int n = blockIdx.x * BN + threadIdx.x;

    const float tau_m    = p_tau[0];
    const float v_th     = p_vth[0];
    const float v_rst    = p_vreset[0];
    const float r_m      = p_rm[0];
    const float v_rest   = p_vrest[0];
    const float refr_set = __fdiv_rn(p_refr[0], 1.0f);
    const int   n_refr   = (int)ceilf(refr_set);
    const float rcp_tau  = __fdiv_rn(1.0f, tau_m);
    const float rcp_1k   = __fdiv_rn(1.0f, 1000.0f);
    const float a_rst    = __fsub_rn(v_rest, v_rst);

    const float* vS = ws + 0 * C_CHUNKS * N_NEURONS;
    const float* pS = ws + 1 * C_CHUNKS * N_NEURONS;
    const int*   rS = (const int*)(ws + 2 * C_CHUNKS * N_NEURONS);
    const float* vE = ws + 3 * C_CHUNKS * N_NEURONS;
    const float* pE = ws + 4 * C_CHUNKS * N_NEURONS;
    const int*   rE = (const int*)(ws + 5 * C_CHUNKS * N_NEURONS);

    // chunk 0 is exact (no speculation): true state after it = E[0]
    float v        = vE[n];
    float prev     = pE[n];
    int   refr_end = rE[n];

    for (int c = 1; c < C_CHUNKS; ++c) {
        const int  sidx  = c * N_NEURONS + n;
        const bool match = (v == vS[sidx]) && (prev == pS[sidx]) &&
                           (refr_end == rS[sidx]);
        bool usespec = match;
        if (!match) {
            // re-simulate chunk c from the true state, patching output
            const int tmain = c * L_CHUNK;
            const int tlast = tmain + L_CHUNK - 1;      // incl. prev-producing step
            out[(size_t)n * T_STEPS + tmain] = prev;    // column tmain = sp(tmain-1)
            float a = __fsub_rn(v_rest, v);             // exact reconstruction of a
            bool merged = false;
            for (int t = tmain; t <= tlast; ++t) {
                if (t > T_STEPS - 2) break;             // step T-1 never executed
                const float xi = I[(size_t)n * T_STEPS + t];
                const float w  = __fmul_rn(r_m, div_rn_fast(xi, 1000.0f, rcp_1k));
                bool sp;
                LIF_STEP(w, t, v, a, refr_end, sp);
                const float spf = sp ? 1.0f : 0.0f;
                prev = spf;
                if (t <= tlast - 1) {                   // owned columns only
                    const size_t oc   = (size_t)n * T_STEPS + t + 1;
                    const float specv = out[oc];        // speculative value
                    out[oc] = spf;
                    if (sp && specv == 1.0f) {          // coincident spike:
                        merged = true;                  // states provably equal
                        break;                          // rest of chunk is exact
                    }
                }
            }
            usespec = merged;
        }
        if (usespec) {                                  // adopt pass-1 exit state
            v = vE[sidx]; prev = pE[sidx]; refr_end = rE[sidx];
        }
        // else: state already true from the re-simulation
    }
}

extern "C" void kernel_launch(void* const* d_in, const int* in_sizes, int n_in,
                              void* d_out, int out_size, void* d_ws, size_t ws_size,
                              hipStream_t stream)
{
    const float* I = (const float*)d_in[0];
    float* out = (float*)d_out;
    float* ws  = (float*)d_ws;    // needs 6 * 32 * 4096 * 4 B = 3 MiB

    lif_pass1<<<dim3((N_NEURONS / BN) * C_CHUNKS), dim3(BN), 0, stream>>>(
        I, (const float*)d_in[1], (const float*)d_in[2], (const float*)d_in[3],
        (const float*)d_in[4], (const float*)d_in[5], (const float*)d_in[6],
        out, ws);

    lif_pass2<<<dim3(N_NEURONS / BN), dim3(BN), 0, stream>>>(
        I, (const float*)d_in[1], (const float*)d_in[2], (const float*)d_in[3],
        (const float*)d_in[4], (const float*)d_in[5], (const float*)d_in[6],
        out, ws);
}

// Round 7
// 372.522 us; speedup vs baseline: 8.0570x; 8.0570x over previous
//
#include <hip/hip_runtime.h>

// LIF neuron scan, speculative time-chunked (two-pass), bit-exact.
//
// R5 post-mortem: match rate ~0% because refr_end is an ABSOLUTE spike time --
// true state carries the timestamp of the last spike ever; warmup carries its
// init value. Both stale (<= chunk start) => semantically identical, but the
// bit compare failed => everything re-simulated serially with scalar loads
// (2750 us). Fixes this round:
//   (1) refr_end compared in its exactness-preserving equivalence class:
//       any value <= tmain is inert for all t >= tmain;
//   (2) W=512 warmup (sparse spikes => merging is contraction + ulp-dither,
//       needs ~300-400 steps, not coincident resets);
//   (3) pass2 re-sim uses the same prefetched float4 ping-pong as pass1.
//
// Correctness never depends on speculation: pass2 carries the true running
// state; a chunk is adopted only if the true state matches the chunk's
// recorded entry state (bitwise, modulo the refr equivalence class, which is
// exact). Otherwise the chunk is re-simulated with identical rounded ops.
// Numerics = the absmax-0.0-validated R4 step: _rn intrinsics in reference
// order, Markstein 2-FMA correctly-rounded divisions, integer refractory
// end-time (exactly ceil(refr/DT) clamped steps per spike).

#define N_NEURONS 4096
#define T_STEPS   8192
#define BN        64                       // threads per block = 1 wave
#define L_CHUNK   256                      // steps per chunk
#define W_WARM    512                      // warmup steps (clamped at t=0)
#define C_CHUNKS  (T_STEPS / L_CHUNK)      // 32
#define CN        (C_CHUNKS * N_NEURONS)

struct LifConst {
    float tau_m, v_th, v_rst, r_m, v_rest, a_rst, rcp_tau, rcp_1k;
    int   n_refr;
};

__device__ __forceinline__ float div_rn_fast(float a, float b, float rb) {
    // rb = RN(1/b), b normal; returns RN(a/b) for normal a,b,quotient (Markstein).
    const float q = __fmul_rn(a, rb);
    const float e = __fmaf_rn(-b, q, a);
    return __fmaf_rn(e, rb, q);
}

__device__ __forceinline__ LifConst load_consts(const float* p_tau,
        const float* p_vth, const float* p_vreset, const float* p_rm,
        const float* p_vrest, const float* p_refr) {
    LifConst K;
    K.tau_m = p_tau[0]; K.v_th = p_vth[0]; K.v_rst = p_vreset[0];
    K.r_m = p_rm[0];    K.v_rest = p_vrest[0];
    const float refr_set = __fdiv_rn(p_refr[0], 1.0f);   // refractory / DT
    K.n_refr  = (int)ceilf(refr_set);                    // exact in-refr steps
    K.rcp_tau = __fdiv_rn(1.0f, K.tau_m);
    K.rcp_1k  = __fdiv_rn(1.0f, 1000.0f);
    K.a_rst   = __fsub_rn(K.v_rest, K.v_rst);
    return K;
}

// one exact LIF step (bit-identical to reference); returns spike
__device__ __forceinline__ bool lif_step(const LifConst& K, float w, int t,
                                         float& v, float& a, int& refr_end) {
    const bool  inr   = t < refr_end;
    const float u     = __fadd_rn(a, w);                       // RN(a + w)
    const float dv    = div_rn_fast(u, K.tau_m, K.rcp_tau);    // RN(u/tau)
    const float vi    = __fadd_rn(v, dv);
    const bool  cross = vi >= K.v_th;
    const bool  rst   = inr || cross;
    const float a_ch  = __fsub_rn(K.v_rest, vi);               // parallel w/ cmp
    v = rst ? K.v_rst : vi;
    a = rst ? K.a_rst : a_ch;
    const bool sp = (!inr) && cross;
    refr_end = sp ? (t + 1 + K.n_refr) : refr_end;
    return sp;
}

__device__ __forceinline__ void load_group(const float4* __restrict__ rowI4,
                                           int tb, float4 buf[8]) {
    #pragma unroll
    for (int j = 0; j < 8; ++j) buf[j] = rowI4[tb / 4 + j];
}

// simulate 32 steps from buf (raw I values); STORE => write spike columns
template <bool STORE>
__device__ __forceinline__ void sim_group32(const LifConst& K,
        const float4 buf[8], int tb, float4* __restrict__ rowO4,
        float& v, float& a, int& refr_end, float& prev) {
    #pragma unroll
    for (int j = 0; j < 8; ++j) {
        const float4 x  = buf[j];
        const int    c0 = tb + 4 * j;
        float4 s;
        s.x = prev;                        // col c0 = spike of step c0-1
        #pragma unroll
        for (int k = 0; k < 4; ++k) {
            const int t = c0 + k;
            float spf = 0.0f;
            if (t < T_STEPS - 1) {         // uniform guard (last chunk only)
                const float xi = (k == 0) ? x.x : (k == 1) ? x.y : (k == 2) ? x.z : x.w;
                const float w  = __fmul_rn(K.r_m, div_rn_fast(xi, 1000.0f, K.rcp_1k));
                const bool sp  = lif_step(K, w, t, v, a, refr_end);
                spf = sp ? 1.0f : 0.0f;
            }
            if      (k == 0) s.y = spf;
            else if (k == 1) s.z = spf;
            else if (k == 2) s.w = spf;
            else             prev = spf;
        }
        if (STORE) rowO4[c0 / 4] = s;
    }
}

__global__ __launch_bounds__(BN)
void lif_pass1(const float* __restrict__ I,
               const float* __restrict__ p_tau, const float* __restrict__ p_vth,
               const float* __restrict__ p_vreset, const float* __restrict__ p_rm,
               const float* __restrict__ p_vrest, const float* __restrict__ p_refr,
               float* __restrict__ out, float* __restrict__ ws)
{
    const int lane = threadIdx.x;
    const int c    = blockIdx.x & (C_CHUNKS - 1);   // chunk fastest: L2 locality
    const int nb   = blockIdx.x / C_CHUNKS;
    const int n    = nb * BN + lane;

    const LifConst K = load_consts(p_tau, p_vth, p_vreset, p_rm, p_vrest, p_refr);

    const float4* rowI4 = reinterpret_cast<const float4*>(I   + (size_t)n * T_STEPS);
    float4*       rowO4 = reinterpret_cast<float4*>      (out + (size_t)n * T_STEPS);

    const int tmain = c * L_CHUNK;
    const int t0    = (tmain >= W_WARM) ? (tmain - W_WARM) : 0;  // clamp at 0
    const int gmain = (tmain - t0) / 32;            // 0, 8, or 16 (always even)
    const int ngrp  = gmain + L_CHUNK / 32;         // + 8 main groups

    float v, a, prev;
    int   refr_end;
    if (c == 0) {   // exact start
        v = K.v_rest; a = __fsub_rn(K.v_rest, K.v_rest); refr_end = 0; prev = 0.0f;
    } else {        // canonical guess; warmup contracts to the true trajectory
        v = K.v_rst;  a = K.a_rst;  refr_end = t0;  prev = 0.0f;
    }

    float* vS = ws + 0 * CN;  float* pS = ws + 1 * CN;
    int*   rS = (int*)(ws + 2 * CN);
    float* vE = ws + 3 * CN;  float* pE = ws + 4 * CN;
    int*   rE = (int*)(ws + 5 * CN);
    const int sidx = c * N_NEURONS + n;

    float4 bufA[8], bufB[8];                        // static refs only (rule #20)
    load_group(rowI4, t0, bufA);

    // ---- warmup groups [0, gmain), no stores; even count, ping-pong pairs
    for (int p = 0; p < gmain / 2; ++p) {
        const int gA = 2 * p, gB = 2 * p + 1;
        load_group(rowI4, t0 + gB * 32, bufB);
        sim_group32<false>(K, bufA, t0 + gA * 32, rowO4, v, a, refr_end, prev);
        load_group(rowI4, t0 + (gB + 1) * 32, bufA);   // gB+1 <= gmain < ngrp
        sim_group32<false>(K, bufB, t0 + gB * 32, rowO4, v, a, refr_end, prev);
    }

    vS[sidx] = v; pS[sidx] = prev; rS[sidx] = refr_end;   // entry state S[c]

    // ---- main groups [gmain, ngrp), stores on; bufA already holds gmain
    for (int p = 0; p < 4; ++p) {
        const int gA = gmain + 2 * p, gB = gA + 1;
        load_group(rowI4, t0 + gB * 32, bufB);
        sim_group32<true>(K, bufA, t0 + gA * 32, rowO4, v, a, refr_end, prev);
        if (gB + 1 < ngrp) load_group(rowI4, t0 + (gB + 1) * 32, bufA);
        sim_group32<true>(K, bufB, t0 + gB * 32, rowO4, v, a, refr_end, prev);
    }

    vE[sidx] = v; pE[sidx] = prev; rE[sidx] = refr_end;   // exit state E[c]
}

__global__ __launch_bounds__(BN)
void lif_pass2(const float* __restrict__ I,
               const float* __restrict__ p_tau, const float* __restrict__ p_vth,
               const float* __restrict__ p_vreset, const float* __restrict__ p_rm,
               const float* __restrict__ p_vrest, const float* __restrict__ p_refr,
               float* __restrict__ out, const float* __restrict__ ws)
{
    const int n = blockIdx.x * BN + threadIdx.x;

    const LifConst K = load_consts(p_tau, p_vth, p_vreset, p_rm, p_vrest, p_refr);

    const float4* rowI4 = reinterpret_cast<const float4*>(I   + (size_t)n * T_STEPS);
    float4*       rowO4 = reinterpret_cast<float4*>      (out + (size_t)n * T_STEPS);

    const float* vS = ws + 0 * CN;  const float* pS = ws + 1 * CN;
    const int*   rS = (const int*)(ws + 2 * CN);
    const float* vE = ws + 3 * CN;  const float* pE = ws + 4 * CN;
    const int*   rE = (const int*)(ws + 5 * CN);

    // chunk 0 is exact: true state after it = E[0]
    float v        = vE[n];
    float prev     = pE[n];
    int   refr_end = rE[n];

    for (int c = 1; c < C_CHUNKS; ++c) {
        const int sidx  = c * N_NEURONS + n;
        const int tmain = c * L_CHUNK;

        const float vs = vS[sidx], ps = pS[sidx];   // coalesced state loads
        const int   rs = rS[sidx];
        const float ve = vE[sidx], pe = pE[sidx];
        const int   re = rE[sidx];

        // refr equivalence class: any refr_end <= tmain is inert for t >= tmain
        const bool refr_ok = (refr_end == rs) ||
                             ((refr_end <= tmain) && (rs <= tmain));
        const bool match   = (v == vs) && (prev == ps) && refr_ok;

        if (match) {
            v = ve; prev = pe; refr_end = re;       // chunk provably exact
        } else {
            // re-simulate chunk c from the true state, overwriting its columns
            float a = __fsub_rn(K.v_rest, v);       // exact (Sterbenz range)
            float4 bufA[8], bufB[8];
            load_group(rowI4, tmain, bufA);
            for (int p = 0; p < 4; ++p) {
                const int gA = 2 * p, gB = gA + 1;
                const int tA = tmain + gA * 32, tB = tmain + gB * 32;
                load_group(rowI4, tB, bufB);
                sim_group32<true>(K, bufA, tA, rowO4, v, a, refr_end, prev);
                if (gB + 1 < 8) load_group(rowI4, tmain + (gB + 1) * 32, bufA);
                sim_group32<true>(K, bufB, tB, rowO4, v, a, refr_end, prev);
            }
        }
    }
}

extern "C" void kernel_launch(void* const* d_in, const int* in_sizes, int n_in,
                              void* d_out, int out_size, void* d_ws, size_t ws_size,
                              hipStream_t stream)
{
    const float* I = (const float*)d_in[0];
    float* out = (float*)d_out;
    float* ws  = (float*)d_ws;    // 6 * 32 * 4096 * 4 B = 3 MiB

    lif_pass1<<<dim3((N_NEURONS / BN) * C_CHUNKS), dim3(BN), 0, stream>>>(
        I, (const float*)d_in[1], (const float*)d_in[2], (const float*)d_in[3],
        (const float*)d_in[4], (const float*)d_in[5], (const float*)d_in[6],
        out, ws);

    lif_pass2<<<dim3(N_NEURONS / BN), dim3(BN), 0, stream>>>(
        I, (const float*)d_in[1], (const float*)d_in[2], (const float*)d_in[3],
        (const float*)d_in[4], (const float*)d_in[5], (const float*)d_in[6],
        out, ws);
}